// Round 3
// baseline (2585.040 us; speedup 1.0000x reference)
//
#include <hip/hip_runtime.h>
#include <cstdint>
#include <cstddef>

#define U4    512   // 4*U
#define UNITS 128
#define BATCH 256
#define TSEQ  512
#define FEAT  64
#define SEQS  8                  // sequences per lstm_rec block (fills 16 A-rows)
#define NBLK  (BATCH / SEQS)     // 32 blocks

typedef short short8 __attribute__((ext_vector_type(8)));
typedef float f32x4  __attribute__((ext_vector_type(4)));

// ---------------- fast activations (fp32, ~1e-7 rel err) ----------------
__device__ __forceinline__ float sigm(float x) {
    float e = __expf(-x);
    return __fdividef(1.0f, 1.0f + e);
}
__device__ __forceinline__ float tanh_fast(float x) {
    float e = __expf(2.0f * x);
    return 1.0f - __fdividef(2.0f, e + 1.0f);
}

// ---------------- bf16 split helpers (RNE) ----------------
__device__ __forceinline__ unsigned short f2bf(float f) {
    unsigned u = __float_as_uint(f);
    unsigned r = u + 0x7FFFu + ((u >> 16) & 1u);
    return (unsigned short)(r >> 16);
}
__device__ __forceinline__ float bf2f(unsigned short h) {
    return __uint_as_float(((unsigned)h) << 16);
}

// ---------------- projection GEMM (unchanged) ----------------
__global__ __launch_bounds__(256, 4)
void proj_gemm(const float* __restrict__ in, const float* __restrict__ W,
               const float* __restrict__ bias, float* __restrict__ out,
               int K, int sB, int sT, int t0, int tcShift)
{
    const int tid = threadIdx.x;
    const int tx = tid & 31;
    const int ty = tid >> 5;
    const int m0 = blockIdx.x * 64;
    const int n0 = blockIdx.y * 128;
    const int TcMask = (1 << tcShift) - 1;

    __shared__ float As[32][68];
    __shared__ float Bs[32][128];

    float4 acc[8];
    #pragma unroll
    for (int i = 0; i < 8; ++i) acc[i] = make_float4(0.f, 0.f, 0.f, 0.f);

    for (int k0 = 0; k0 < K; k0 += 32) {
        #pragma unroll
        for (int i = 0; i < 8; ++i) {
            int l = i * 256 + tid;
            int row = l >> 5, kk = l & 31;
            int rg = m0 + row;
            int b = rg >> tcShift, tc = rg & TcMask;
            As[kk][row] = in[(size_t)b * sB + (size_t)(t0 + tc) * sT + k0 + kk];
        }
        #pragma unroll
        for (int i = 0; i < 4; ++i) {
            int l = i * 256 + tid;
            int kk = l >> 5, jq = l & 31;
            float4 w4 = *(const float4*)(W + (size_t)(k0 + kk) * U4 + n0 + jq * 4);
            *(float4*)(&Bs[kk][jq * 4]) = w4;
        }
        __syncthreads();
        #pragma unroll
        for (int kk = 0; kk < 32; ++kk) {
            float4 b4 = *(const float4*)(&Bs[kk][tx * 4]);
            float4 a0 = *(const float4*)(&As[kk][ty * 8]);
            float4 a1 = *(const float4*)(&As[kk][ty * 8 + 4]);
            float a[8] = {a0.x, a0.y, a0.z, a0.w, a1.x, a1.y, a1.z, a1.w};
            #pragma unroll
            for (int i = 0; i < 8; ++i) {
                acc[i].x = __builtin_fmaf(a[i], b4.x, acc[i].x);
                acc[i].y = __builtin_fmaf(a[i], b4.y, acc[i].y);
                acc[i].z = __builtin_fmaf(a[i], b4.z, acc[i].z);
                acc[i].w = __builtin_fmaf(a[i], b4.w, acc[i].w);
            }
        }
        __syncthreads();
    }

    float4 bb = *(const float4*)(bias + n0 + tx * 4);
    #pragma unroll
    for (int i = 0; i < 8; ++i) {
        int rg = m0 + ty * 8 + i;
        float4 v = acc[i];
        v.x += bb.x; v.y += bb.y; v.z += bb.z; v.w += bb.w;
        *(float4*)(out + (size_t)rg * U4 + n0 + tx * 4) = v;
    }
}

// ---------------- R -> bf16 hi/lo MFMA B-fragments (v5 layout, unchanged) -
// 8 waves/block. Wave w owns units [w*16, w*16+16). Tile g (g=0..3) = gate g
// of those 16 units, lane col m <-> unit w*16+m.
// Frag layout per MFMA (16x16x32 bf16 B): lane holds B[k=kt*32+(lane>>4)*8+j][n=lane&15].
// Rf[layer][w(8)][gate(4)][kt(4)][pass(2)][lane(64)][8 shorts].
__global__ __launch_bounds__(256)
void r_frag(const float* __restrict__ R0, const float* __restrict__ R1,
            const float* __restrict__ R2, unsigned short* __restrict__ out)
{
    int gid = blockIdx.x * 256 + threadIdx.x;    // 3 * 16384
    int l    = gid >> 14;
    int r    = gid & 16383;
    int lane = r & 63;
    int fi   = r >> 6;            // 0..255
    int pass = fi & 1;
    int kt   = (fi >> 1) & 3;
    int gate = (fi >> 3) & 3;
    int w    = fi >> 5;           // 0..7
    const float* R = (l == 0) ? R0 : (l == 1) ? R1 : R2;

    int col = gate * UNITS + w * 16 + (lane & 15);   // original R column
    int k0  = kt * 32 + (lane >> 4) * 8;
    short8 v;
    #pragma unroll
    for (int j = 0; j < 8; ++j) {
        float x = R[(size_t)(k0 + j) * U4 + col];
        unsigned short hi = f2bf(x);
        unsigned short s = pass ? f2bf(x - bf2f(hi)) : hi;
        v[j] = (short)s;
    }
    *(short8*)(out + (size_t)gid * 8) = v;
}

// ---------------- LSTM recurrence via MFMA (v6: 8 seqs/block) ------------
// 32 blocks x 512 threads (8 waves). Block owns seqs [blk*8, blk*8+8).
// A-rows carry 8 sequences: row 2s = h_hi(seq s), row 2s+1 = h_lo(seq s) --
// all 16 MFMA A-rows live (v3/v5 wasted 14/16 rows multiplying zeros).
// Same 256 MFMAs/block/step now serve 8 seqs -> 8x less total MFMA work.
// C-layout (row = 4*quad + reg): lane in quad q holds regs
// {seq 2q hi, seq 2q lo, seq 2q+1 hi, seq 2q+1 lo} -> hi/lo combine is
// IN-LANE (z0=C[0]+C[1], z1=C[2]+C[3]); phase B = 2 unit-seq updates per
// lane, FULL 64-lane exec, no shuffles, no masks, ONE barrier/step.
// xw folded into hi-row C-init (regs 0,2). xw prefetched 2 steps ahead
// (step time << HBM latency now). B-frags/r_frag = v5 validated layout.
__global__ __launch_bounds__(512, 2)
void lstm_rec(const float* __restrict__ xw, const unsigned short* __restrict__ Rf,
              float* __restrict__ h_state, float* __restrict__ c_state,
              float* __restrict__ h_out, int Tc, int init)
{
    const int tid  = threadIdx.x;
    const int blk  = blockIdx.x;
    const int lane = tid & 63;
    const int w    = tid >> 6;       // 0..7, units [w*16, w*16+16)
    const int m    = lane & 15;
    const int quad = lane >> 4;

    // [parity][row 0..15][unit] ; row 2s=hi(seq s), 2s+1=lo(seq s)
    // row stride 136 shorts = 272 B: 16B-aligned, uniform bank spread for
    // ds_read_b128 (slot = (m+quad) & 7 uniform over 8 lanes each).
    __shared__ __align__(16) unsigned short htab[2][16][136];

    // B fragments: [gate][kt][pass] = 32 short8 = 128 regs (v5 layout)
    short8 bf[4][4][2];
    #pragma unroll
    for (int g = 0; g < 4; ++g)
        #pragma unroll
        for (int kt = 0; kt < 4; ++kt)
            #pragma unroll
            for (int pp = 0; pp < 2; ++pp)
                bf[g][kt][pp] = *(const short8*)(
                    Rf + ((size_t)((((w * 4 + g) * 4 + kt) * 2) + pp) * 64 + lane) * 8);

    const int unit = w * 16 + m;
    const int s0   = 2 * quad;       // lane's first local seq
    const int s1   = s0 + 1;

    float c0 = 0.f, c1 = 0.f;
    if (!init) {
        c0 = c_state[(blk * SEQS + s0) * UNITS + unit];
        c1 = c_state[(blk * SEQS + s1) * UNITS + unit];
    }
    // htab init: thread covers seq (tid>>7) and (tid>>7)+4, unit tid&127
    {
        int uu = tid & 127;
        #pragma unroll
        for (int i = 0; i < 2; ++i) {
            int s = (tid >> 7) + i * 4;
            float hv = init ? 0.f : h_state[(blk * SEQS + s) * UNITS + uu];
            unsigned short hi = f2bf(hv);
            htab[0][2 * s][uu]     = hi;
            htab[0][2 * s + 1][uu] = f2bf(hv - bf2f(hi));
        }
    }
    __syncthreads();

    // per-lane xw bases for its two seqs (gate g at +g*128)
    const float* xw0 = xw + (size_t)(blk * SEQS + s0) * Tc * U4 + unit;
    const float* xw1 = xw + (size_t)(blk * SEQS + s1) * Tc * U4 + unit;

    float xa[8], xb[8];   // xa: even steps, xb: odd steps
    #pragma unroll
    for (int g = 0; g < 4; ++g) {
        xa[g]     = xw0[g * UNITS];
        xa[4 + g] = xw1[g * UNITS];
    }
    {
        const size_t o1 = (size_t)((Tc > 1) ? 1 : 0) * U4;
        #pragma unroll
        for (int g = 0; g < 4; ++g) {
            xb[g]     = xw0[o1 + g * UNITS];
            xb[4 + g] = xw1[o1 + g * UNITS];
        }
    }

    float hl0 = 0.f, hl1 = 0.f;

    auto STEP = [&](int t, int p, float (&xc)[8]) {
        // A-frags: lane reads its row m, k = kt*32 + quad*8 (full wave)
        short8 af[4];
        #pragma unroll
        for (int kt = 0; kt < 4; ++kt)
            af[kt] = *(const short8*)(&htab[p][m][kt * 32 + quad * 8]);

        // C init: xw folded into hi rows (regs 0,2); lo rows 0
        f32x4 C0 = {xc[0], 0.f, xc[4], 0.f};
        f32x4 C1 = {xc[1], 0.f, xc[5], 0.f};
        f32x4 C2 = {xc[2], 0.f, xc[6], 0.f};
        f32x4 C3 = {xc[3], 0.f, xc[7], 0.f};

        // prefetch t+2 into xc (C-init already consumed it)
        int tp = t + 2; if (tp >= Tc) tp = Tc - 1;
        const size_t off = (size_t)tp * U4;
        #pragma unroll
        for (int g = 0; g < 4; ++g) {
            xc[g]     = xw0[off + g * UNITS];
            xc[4 + g] = xw1[off + g * UNITS];
        }

        #pragma unroll
        for (int kt = 0; kt < 4; ++kt) {
            #pragma unroll
            for (int pp = 0; pp < 2; ++pp) {
                C0 = __builtin_amdgcn_mfma_f32_16x16x32_bf16(af[kt], bf[0][kt][pp], C0, 0, 0, 0);
                C1 = __builtin_amdgcn_mfma_f32_16x16x32_bf16(af[kt], bf[1][kt][pp], C1, 0, 0, 0);
                C2 = __builtin_amdgcn_mfma_f32_16x16x32_bf16(af[kt], bf[2][kt][pp], C2, 0, 0, 0);
                C3 = __builtin_amdgcn_mfma_f32_16x16x32_bf16(af[kt], bf[3][kt][pp], C3, 0, 0, 0);
            }
        }

        // ---- phase B: in-lane hi+lo combine, 2 unit-seq updates ----
        float zi0 = C0.x + C0.y, zi1 = C0.z + C0.w;
        float zf0 = C1.x + C1.y, zf1 = C1.z + C1.w;
        float zg0 = C2.x + C2.y, zg1 = C2.z + C2.w;
        float zo0 = C3.x + C3.y, zo1 = C3.z + C3.w;

        float iv0 = sigm(zi0), fv0 = sigm(zf0);
        float gv0 = tanh_fast(zg0), ov0 = sigm(zo0);
        c0 = __builtin_fmaf(fv0, c0, iv0 * gv0);
        float hv0 = ov0 * tanh_fast(c0);

        float iv1 = sigm(zi1), fv1 = sigm(zf1);
        float gv1 = tanh_fast(zg1), ov1 = sigm(zo1);
        c1 = __builtin_fmaf(fv1, c1, iv1 * gv1);
        float hv1 = ov1 * tanh_fast(c1);

        hl0 = hv0; hl1 = hv1;

        unsigned short hi0 = f2bf(hv0);
        htab[p ^ 1][4 * quad + 0][unit] = hi0;
        htab[p ^ 1][4 * quad + 1][unit] = f2bf(hv0 - bf2f(hi0));
        unsigned short hi1 = f2bf(hv1);
        htab[p ^ 1][4 * quad + 2][unit] = hi1;
        htab[p ^ 1][4 * quad + 3][unit] = f2bf(hv1 - bf2f(hi1));

        if (h_out) {
            h_out[((size_t)(blk * SEQS + s0) * Tc + t) * UNITS + unit] = hv0;
            h_out[((size_t)(blk * SEQS + s1) * Tc + t) * UNITS + unit] = hv1;
        }
        __syncthreads();   // htab[p^1] ready for next step
    };

    #pragma unroll 1
    for (int t = 0; t < Tc; t += 2) {
        STEP(t,     0, xa);
        STEP(t + 1, 1, xb);
    }

    c_state[(blk * SEQS + s0) * UNITS + unit] = c0;
    c_state[(blk * SEQS + s1) * UNITS + unit] = c1;
    h_state[(blk * SEQS + s0) * UNITS + unit] = hl0;
    h_state[(blk * SEQS + s1) * UNITS + unit] = hl1;
}

// ---------------- dense head ----------------
__global__ __launch_bounds__(256)
void dense_head(const float* __restrict__ h2, const float* __restrict__ Wd,
                const float* __restrict__ bd, float* __restrict__ out)
{
    int b = threadIdx.x;
    float acc[6];
    #pragma unroll
    for (int o = 0; o < 6; ++o) acc[o] = bd[o];
    #pragma unroll 4
    for (int k = 0; k < UNITS; ++k) {
        float hv = h2[b * UNITS + k];
        #pragma unroll
        for (int o = 0; o < 6; ++o)
            acc[o] = __builtin_fmaf(hv, Wd[k * 6 + o], acc[o]);
    }
    #pragma unroll
    for (int o = 0; o < 6; ++o) out[b * 6 + o] = acc[o];
}

extern "C" void kernel_launch(void* const* d_in, const int* in_sizes, int n_in,
                              void* d_out, int out_size, void* d_ws, size_t ws_size,
                              hipStream_t stream)
{
    (void)in_sizes; (void)n_in; (void)out_size;
    const float* x  = (const float*)d_in[0];
    const float* Ws[3] = {(const float*)d_in[1], (const float*)d_in[4], (const float*)d_in[7]};
    const float* Rs[3] = {(const float*)d_in[2], (const float*)d_in[5], (const float*)d_in[8]};
    const float* bs[3] = {(const float*)d_in[3], (const float*)d_in[6], (const float*)d_in[9]};
    const float* Wd = (const float*)d_in[10];
    const float* bd = (const float*)d_in[11];
    float* out = (float*)d_out;

    int tcShift = 7;
    while (tcShift > 2) {
        size_t need = ((size_t)1 << tcShift) * 655360u + 786432u + 786432u;
        if (need <= ws_size) break;
        --tcShift;
    }
    const int Tc = 1 << tcShift;

    float* xw = (float*)d_ws;                                // [B][Tc][512]
    float* hc = xw + (size_t)BATCH * Tc * U4;                // [B][Tc][128]
    float* hs = hc + (size_t)BATCH * Tc * UNITS;             // 3 x [B][128]
    float* cs = hs + 3 * BATCH * UNITS;                      // 3 x [B][128]
    unsigned short* Rf = (unsigned short*)(cs + 3 * BATCH * UNITS); // 3 x 128K shorts

    // precompute v5-permuted bf16 hi/lo MFMA B-fragments of R0..R2
    r_frag<<<192, 256, 0, stream>>>(Rs[0], Rs[1], Rs[2], Rf);

    const int nChunks = TSEQ / Tc;
    for (int ch = 0; ch < nChunks; ++ch) {
        const int t0 = ch * Tc;
        for (int layer = 0; layer < 3; ++layer) {
            const float* in = (layer == 0) ? x : hc;
            const int K  = (layer == 0) ? FEAT : UNITS;
            const int sB = (layer == 0) ? TSEQ * FEAT : Tc * UNITS;
            const int sT = K;
            const int pt0 = (layer == 0) ? t0 : 0;

            dim3 grid(BATCH * Tc / 64, 4);
            proj_gemm<<<grid, 256, 0, stream>>>(in, Ws[layer], bs[layer], xw,
                                                K, sB, sT, pt0, tcShift);

            float* hOut = (layer < 2) ? hc : nullptr;
            lstm_rec<<<NBLK, 512, 0, stream>>>(xw, Rf + (size_t)layer * 131072,
                                               hs + layer * BATCH * UNITS,
                                               cs + layer * BATCH * UNITS,
                                               hOut, Tc, (ch == 0) ? 1 : 0);
        }
    }
    dense_head<<<1, 256, 0, stream>>>(hs + 2 * BATCH * UNITS, Wd, bd, out);
}